// Round 2
// baseline (346.236 us; speedup 1.0000x reference)
//
#include <hip/hip_runtime.h>

// MultiHeadAttention3D: S=1024, B=8, E=1024, H=16, D=64.
// Pipeline: cvt(f32->bf16) -> 3x proj GEMM (m97-style) -> mask-dtype detect ->
//           V transpose -> fused flash attention (swapped-QK, O^T accumulation) -> Wo GEMM.

typedef __attribute__((ext_vector_type(8))) short bf16x8;       // MFMA A/B frag (8 bf16)
typedef __attribute__((ext_vector_type(8))) unsigned short u16x8;
typedef __attribute__((ext_vector_type(4))) float f32x4;

#define LOG2E 1.44269504088896340736f

__device__ __forceinline__ unsigned short bfbits(float f) {    // f32 -> bf16 (RTNE)
  unsigned u = __builtin_bit_cast(unsigned, f);
  u += 0x7fffu + ((u >> 16) & 1u);
  return (unsigned short)(u >> 16);
}
__device__ __forceinline__ unsigned pk2(float a, float b) {    // two bf16 packed in u32
  return (unsigned)bfbits(a) | ((unsigned)bfbits(b) << 16);
}
__device__ __forceinline__ void async16(const void* src, void* dst_lds) {
  // 16B global->LDS DMA; LDS dest is wave-uniform base + lane*16
  __builtin_amdgcn_global_load_lds(
      (const __attribute__((address_space(1))) unsigned int*)src,
      (__attribute__((address_space(3))) unsigned int*)dst_lds, 16, 0, 0);
}

// ---------------- convert q,k,v,W* to bf16 ----------------
__global__ __launch_bounds__(256) void cvt_kernel(
    const float* __restrict__ q, const float* __restrict__ k, const float* __restrict__ v,
    const float* __restrict__ wq, const float* __restrict__ wk,
    const float* __restrict__ wv, const float* __restrict__ wo,
    unsigned short* __restrict__ Xin, unsigned short* __restrict__ Wbf)
{
  const unsigned u = blockIdx.x * 256u + threadIdx.x;   // exactly 3670016 units of 8 elems
  const float* src;
  unsigned short* dst;
  if (u < 3145728u) {                      // q,k,v: 3 x 1048576 units
    const unsigned z = u >> 20, r = u & 1048575u;
    src = (z == 0 ? q : z == 1 ? k : v) + (size_t)r * 8;
    dst = Xin + (size_t)z * 8388608u + (size_t)r * 8;
  } else {                                 // Wq,Wk,Wv,Wo: 4 x 131072 units
    const unsigned u2 = u - 3145728u, wz = u2 >> 17, r = u2 & 131071u;
    src = (wz == 0 ? wq : wz == 1 ? wk : wz == 2 ? wv : wo) + (size_t)r * 8;
    dst = Wbf + (size_t)wz * 1048576u + (size_t)r * 8;
  }
  f32x4 a = *(const f32x4*)src;
  f32x4 b = *(const f32x4*)(src + 4);
  u16x8 o;
  o[0]=bfbits(a[0]); o[1]=bfbits(a[1]); o[2]=bfbits(a[2]); o[3]=bfbits(a[3]);
  o[4]=bfbits(b[0]); o[5]=bfbits(b[1]); o[6]=bfbits(b[2]); o[7]=bfbits(b[3]);
  *(u16x8*)dst = o;
}

// ---------------- mask dtype detection ----------------
// If the first 4096 u32 words are all in {0,1}, the mask is int32 (bool would be
// random bytes). 1 wave, writes flag.
__global__ void detect_mask(const unsigned* __restrict__ m, int* __restrict__ flag)
{
  unsigned ok = 1u;
#pragma unroll 8
  for (int i = 0; i < 64; ++i) {
    unsigned w = m[(threadIdx.x << 6) + i];
    ok &= (w <= 1u) ? 1u : 0u;
  }
  unsigned long long vote = __ballot(ok != 0u);
  if (threadIdx.x == 0) *flag = (vote == ~0ull) ? 1 : 0;
}

// ---------------- C[r][e] = sum_c A[r][c]*B[e][c]  (both bf16, K-contiguous) ----------------
// 128x128 tile, 4 waves (2x2 of 64x64), BK=32, global_load_lds staging (m97 structure).
template<int OUTF32>
__global__ __launch_bounds__(256) void gemm_bt(
    const unsigned short* __restrict__ A,  // [M][K]
    const unsigned short* __restrict__ B,  // [N][K]
    void* __restrict__ Cv, float scale, int M, int N, int K)
{
  const int tid = threadIdx.x;
  const int w = tid >> 6, lane = tid & 63, c = lane & 15, g = lane >> 4;
  const int wr = w >> 1, wc = w & 1;
  const int bx = blockIdx.x, by = blockIdx.y;
  __shared__ unsigned short As[128 * 32];
  __shared__ unsigned short Bs[128 * 32];
  f32x4 acc[4][4];
#pragma unroll
  for (int i = 0; i < 4; ++i)
#pragma unroll
    for (int j = 0; j < 4; ++j) acc[i][j] = (f32x4){0.f, 0.f, 0.f, 0.f};

  const int rowA = by * 128, rowB = bx * 128;
  const int sr = tid >> 2, sc = tid & 3;          // slot row / 16B-chunk
  const int ldsbase = (tid & ~63) * 16;           // wave-uniform byte base
  const int nk = K >> 5;
  for (int kt = 0; kt < nk; ++kt) {
    const int k0 = kt << 5;
#pragma unroll
    for (int i = 0; i < 2; ++i) {
      const int r = (i << 6) + sr;                // rows 0..127
      async16(A + (size_t)(rowA + r) * K + k0 + sc * 8, (char*)As + i * 4096 + ldsbase);
      async16(B + (size_t)(rowB + r) * K + k0 + sc * 8, (char*)Bs + i * 4096 + ldsbase);
    }
    __syncthreads();
    bf16x8 af[4], bfr[4];
#pragma unroll
    for (int mf = 0; mf < 4; ++mf)
      af[mf] = *(const bf16x8*)&As[(wr * 64 + mf * 16 + c) * 32 + g * 8];
#pragma unroll
    for (int nf = 0; nf < 4; ++nf)
      bfr[nf] = *(const bf16x8*)&Bs[(wc * 64 + nf * 16 + c) * 32 + g * 8];
#pragma unroll
    for (int mf = 0; mf < 4; ++mf)
#pragma unroll
      for (int nf = 0; nf < 4; ++nf)
        acc[mf][nf] = __builtin_amdgcn_mfma_f32_16x16x32_bf16(af[mf], bfr[nf], acc[mf][nf], 0, 0, 0);
    __syncthreads();
  }
  const int r0 = rowA + wr * 64, c0 = rowB + wc * 64;
  if (OUTF32) {
    float* O = (float*)Cv;
#pragma unroll
    for (int mf = 0; mf < 4; ++mf)
#pragma unroll
      for (int nf = 0; nf < 4; ++nf)
#pragma unroll
        for (int j = 0; j < 4; ++j)
          O[(size_t)(r0 + mf * 16 + g * 4 + j) * N + c0 + nf * 16 + c] = acc[mf][nf][j] * scale;
  } else {
    unsigned short* O = (unsigned short*)Cv;
#pragma unroll
    for (int mf = 0; mf < 4; ++mf)
#pragma unroll
      for (int nf = 0; nf < 4; ++nf)
#pragma unroll
        for (int j = 0; j < 4; ++j)
          O[(size_t)(r0 + mf * 16 + g * 4 + j) * N + c0 + nf * 16 + c] = bfbits(acc[mf][nf][j] * scale);
  }
}

// ---------------- Vt[bh][d][s] = Vproj[(s*8+b)][h*64+d] ----------------
__global__ __launch_bounds__(256) void transpose_v(
    const unsigned short* __restrict__ Xp2, unsigned short* __restrict__ Vt)
{
  const int tid = threadIdx.x;
  const int bh = blockIdx.y, b = bh >> 4, h = bh & 15;
  const int s0 = blockIdx.x << 6;
  __shared__ unsigned short T[64 * 68];
#pragma unroll
  for (int p = 0; p < 2; ++p) {
    const int idx = (p << 8) + tid, sr = idx >> 3, ch2 = idx & 7;
    *(u16x8*)&T[sr * 68 + ch2 * 8] =
        *(const u16x8*)(Xp2 + ((size_t)((s0 + sr) * 8 + b) << 10) + (h << 6) + ch2 * 8);
  }
  __syncthreads();
#pragma unroll
  for (int p = 0; p < 2; ++p) {
    const int idx = (p << 8) + tid, dr = idx >> 3, ch2 = idx & 7;
    u16x8 o;
#pragma unroll
    for (int e = 0; e < 8; ++e) o[e] = T[(ch2 * 8 + e) * 68 + dr];
    *(u16x8*)(Vt + ((size_t)(bh * 64 + dr) << 10) + s0 + ch2 * 8) = o;
  }
}

// ---------------- fused flash attention ----------------
// grid (16 qblocks, 128 bh), 256 thr. Wave w owns q-rows [qb0+16w, +16).
// S^T = K*Q^T (swapped: softmax rows lane-local, q = lane&15).
// O^T = V^T * P^T (rescale/normalize lane-local). P relayout via per-wave LDS bounce.
__global__ __launch_bounds__(256) void attn_kernel(
    const unsigned short* __restrict__ Qp,   // [8192][1024] bf16, pre-scaled by 1/8
    const unsigned short* __restrict__ Kp,   // [8192][1024] bf16
    const unsigned short* __restrict__ Vt,   // [128][64][1024] bf16
    const void*           __restrict__ maskp,// [128][1024][1024] u8 or i32 (nonzero = masked)
    const int*            __restrict__ mflag,// 1 if mask is int32
    unsigned short* __restrict__ AO)         // [8192][1024] bf16
{
  const int tid = threadIdx.x;
  const int w = tid >> 6, lane = tid & 63, c = lane & 15, g = lane >> 4;
  const int bh = blockIdx.y, b = bh >> 4, h = bh & 15;
  const int qb0 = blockIdx.x << 6;
  const int qrow = qb0 + (w << 4) + c;
  const bool mi32 = (*mflag != 0);

  __shared__ unsigned short Ksm[64 * 72];       // [kk][d]
  __shared__ unsigned short Vsm[64 * 72];       // [d][kk]
  __shared__ unsigned short Psm[4][16 * 72];    // per-wave P[q][kk]

  bf16x8 qf[2];
  {
    const unsigned short* qp = Qp + ((size_t)(qrow * 8 + b) << 10) + (h << 6) + (g << 3);
    qf[0] = *(const bf16x8*)qp;
    qf[1] = *(const bf16x8*)(qp + 32);
  }

  const int row0 = tid >> 3, ch = tid & 7;       // staging: rows 0..31 (+32 for pass 1)
  const unsigned short* Vg = Vt + ((size_t)bh << 16);

  bf16x8 kr[2], vr[2];
#pragma unroll
  for (int p = 0; p < 2; ++p) {
    const int r = row0 + p * 32;
    kr[p] = *(const bf16x8*)(Kp + ((size_t)(r * 8 + b) << 10) + (h << 6) + (ch << 3));
    vr[p] = *(const bf16x8*)(Vg + ((size_t)r << 10) + (ch << 3));
  }

  f32x4 oacc[4];
#pragma unroll
  for (int i = 0; i < 4; ++i) oacc[i] = (f32x4){0.f, 0.f, 0.f, 0.f};
  float mrun = -1e30f, lrun = 0.f;

  for (int t = 0; t < 16; ++t) {
    const int kk0 = t << 6;
    __syncthreads();
#pragma unroll
    for (int p = 0; p < 2; ++p) {
      const int r = row0 + p * 32;
      *(bf16x8*)&Ksm[r * 72 + (ch << 3)] = kr[p];
      *(bf16x8*)&Vsm[r * 72 + (ch << 3)] = vr[p];
    }
    __syncthreads();
    if (t < 15) {                                // prefetch next tile into regs
      const int kk1 = kk0 + 64;
#pragma unroll
      for (int p = 0; p < 2; ++p) {
        const int r = row0 + p * 32;
        kr[p] = *(const bf16x8*)(Kp + ((size_t)((kk1 + r) * 8 + b) << 10) + (h << 6) + (ch << 3));
        vr[p] = *(const bf16x8*)(Vg + ((size_t)r << 10) + kk1 + (ch << 3));
      }
    }
    unsigned mv[4];
    if (mi32) {
      const int* mrow = (const int*)maskp + ((size_t)bh << 20) + ((size_t)qrow << 10) + kk0 + (g << 2);
#pragma unroll
      for (int mf = 0; mf < 4; ++mf) {
        const int4 w4 = *(const int4*)(mrow + mf * 16);
        mv[mf] = (w4.x ? 1u : 0u) | (w4.y ? 0x100u : 0u) | (w4.z ? 0x10000u : 0u) | (w4.w ? 0x1000000u : 0u);
      }
    } else {
      const unsigned char* mrow = (const unsigned char*)maskp + ((size_t)bh << 20) + ((size_t)qrow << 10) + kk0 + (g << 2);
#pragma unroll
      for (int mf = 0; mf < 4; ++mf) mv[mf] = *(const unsigned*)(mrow + mf * 16);
    }
    // S^T tile: rows kk = mf*16+g*4+j, col q = c
    f32x4 sacc[4];
#pragma unroll
    for (int i = 0; i < 4; ++i) sacc[i] = (f32x4){0.f, 0.f, 0.f, 0.f};
#pragma unroll
    for (int d2 = 0; d2 < 2; ++d2) {
#pragma unroll
      for (int mf = 0; mf < 4; ++mf) {
        bf16x8 kf = *(const bf16x8*)&Ksm[(mf * 16 + c) * 72 + d2 * 32 + (g << 3)];
        sacc[mf] = __builtin_amdgcn_mfma_f32_16x16x32_bf16(kf, qf[d2], sacc[mf], 0, 0, 0);
      }
    }
    // mask + online softmax (per q=c, reduce over kk: in-lane + xor16 + xor32)
    float tmax = -1e30f;
#pragma unroll
    for (int mf = 0; mf < 4; ++mf)
#pragma unroll
      for (int j = 0; j < 4; ++j) {
        float s = sacc[mf][j];
        if ((mv[mf] >> (8 * j)) & 0xffu) s = -1e30f;
        sacc[mf][j] = s;
        tmax = fmaxf(tmax, s);
      }
    tmax = fmaxf(tmax, __shfl_xor(tmax, 16));
    tmax = fmaxf(tmax, __shfl_xor(tmax, 32));
    const float mnew = fmaxf(mrun, tmax);
    const float alpha = __builtin_amdgcn_exp2f((mrun - mnew) * LOG2E);
    float tsum = 0.f;
    float pv[4][4];
#pragma unroll
    for (int mf = 0; mf < 4; ++mf)
#pragma unroll
      for (int j = 0; j < 4; ++j) {
        const float p = __builtin_amdgcn_exp2f((sacc[mf][j] - mnew) * LOG2E);
        pv[mf][j] = p;
        tsum += p;
      }
    tsum += __shfl_xor(tsum, 16);
    tsum += __shfl_xor(tsum, 32);
    lrun = lrun * alpha + tsum;
    mrun = mnew;
#pragma unroll
    for (int i = 0; i < 4; ++i) {
      oacc[i][0] *= alpha; oacc[i][1] *= alpha; oacc[i][2] *= alpha; oacc[i][3] *= alpha;
    }
    // bounce P^T (regs) -> P[q=c][kk] in per-wave LDS
#pragma unroll
    for (int mf = 0; mf < 4; ++mf) {
      uint2 t2;
      t2.x = pk2(pv[mf][0], pv[mf][1]);
      t2.y = pk2(pv[mf][2], pv[mf][3]);
      *(uint2*)&Psm[w][c * 72 + mf * 16 + (g << 2)] = t2;
    }
    // O^T += V^T * P^T
#pragma unroll
    for (int ks = 0; ks < 2; ++ks) {
      bf16x8 pf = *(const bf16x8*)&Psm[w][c * 72 + ks * 32 + (g << 3)];
#pragma unroll
      for (int mf = 0; mf < 4; ++mf) {
        bf16x8 vf = *(const bf16x8*)&Vsm[(mf * 16 + c) * 72 + ks * 32 + (g << 3)];
        oacc[mf] = __builtin_amdgcn_mfma_f32_16x16x32_bf16(vf, pf, oacc[mf], 0, 0, 0);
      }
    }
  }
  const float inv = 1.0f / lrun;
#pragma unroll
  for (int mf = 0; mf < 4; ++mf) {
    uint2 t2;
    t2.x = pk2(oacc[mf][0] * inv, oacc[mf][1] * inv);
    t2.y = pk2(oacc[mf][2] * inv, oacc[mf][3] * inv);
    *(uint2*)(AO + ((size_t)(qrow * 8 + b) << 10) + (h << 6) + mf * 16 + (g << 2)) = t2;
  }
}

// ---------------- host ----------------
extern "C" void kernel_launch(void* const* d_in, const int* in_sizes, int n_in,
                              void* d_out, int out_size, void* d_ws, size_t ws_size,
                              hipStream_t stream)
{
  const float* q  = (const float*)d_in[0];
  const float* k  = (const float*)d_in[1];
  const float* v  = (const float*)d_in[2];
  const void*  mask = (const void*)d_in[3];
  const float* wq = (const float*)d_in[4];
  const float* wk = (const float*)d_in[5];
  const float* wv = (const float*)d_in[6];
  const float* wo = (const float*)d_in[7];

  unsigned short* ws  = (unsigned short*)d_ws;   // needs 104 MiB
  unsigned short* Xin = ws;                      // 3 x 8388608 (bf16 q,k,v)
  unsigned short* Wbf = ws + 25165824u;          // 4 x 1048576
  unsigned short* Xp  = ws + 29360128u;          // 3 x 8388608 (projected)
  unsigned short* Vt  = ws + 8388608u;           // aliases Xin[1] (dead after K projection)
  unsigned short* AO  = ws;                      // aliases Xin[0] (dead after Q projection)
  int* mfl            = (int*)(ws + 16777216u);  // aliases Xin[2] (dead after V projection)

  cvt_kernel<<<14336, 256, 0, stream>>>(q, k, v, wq, wk, wv, wo, Xin, Wbf);
  gemm_bt<0><<<dim3(8, 64), 256, 0, stream>>>(Xin,              Wbf,            Xp,              0.125f, 8192, 1024, 1024);
  gemm_bt<0><<<dim3(8, 64), 256, 0, stream>>>(Xin + 8388608u,   Wbf + 1048576u, Xp + 8388608u,   1.0f,   8192, 1024, 1024);
  gemm_bt<0><<<dim3(8, 64), 256, 0, stream>>>(Xin + 16777216u,  Wbf + 2097152u, Xp + 16777216u,  1.0f,   8192, 1024, 1024);
  detect_mask<<<1, 64, 0, stream>>>((const unsigned*)mask, mfl);
  transpose_v<<<dim3(16, 128), 256, 0, stream>>>(Xp + 16777216u, Vt);
  attn_kernel<<<dim3(16, 128), 256, 0, stream>>>(Xp, Xp + 8388608u, Vt, mask, mfl, AO);
  gemm_bt<1><<<dim3(8, 64), 256, 0, stream>>>(AO, Wbf + 3145728u, d_out, 1.0f, 8192, 1024, 1024);
}

// Round 3
// 311.641 us; speedup vs baseline: 1.1110x; 1.1110x over previous
//
#include <hip/hip_runtime.h>

// MultiHeadAttention3D: S=1024, B=8, E=1024, H=16, D=64.
// Pipeline: cvt(f32->bf16) -> 3x proj GEMM (2-phase dbuf 256x128) -> mask detect ->
//           V transpose -> fused flash attention (swapped-QK, O^T accum, mask prefetch)
//           -> Wo GEMM (f32 out).

typedef __attribute__((ext_vector_type(8))) short bf16x8;       // MFMA A/B frag (8 bf16)
typedef __attribute__((ext_vector_type(8))) unsigned short u16x8;
typedef __attribute__((ext_vector_type(4))) float f32x4;

#define LOG2E 1.44269504088896340736f

__device__ __forceinline__ unsigned short bfbits(float f) {    // f32 -> bf16 (RTNE)
  unsigned u = __builtin_bit_cast(unsigned, f);
  u += 0x7fffu + ((u >> 16) & 1u);
  return (unsigned short)(u >> 16);
}
__device__ __forceinline__ unsigned pk2(float a, float b) {
  return (unsigned)bfbits(a) | ((unsigned)bfbits(b) << 16);
}
__device__ __forceinline__ void async16(const void* src, void* dst_lds) {
  // 16B global->LDS DMA; LDS dest is wave-uniform base + lane*16
  __builtin_amdgcn_global_load_lds(
      (const __attribute__((address_space(1))) unsigned int*)src,
      (__attribute__((address_space(3))) unsigned int*)dst_lds, 16, 0, 0);
}

// ---------------- convert q,k,v,W* to bf16 ----------------
__global__ __launch_bounds__(256) void cvt_kernel(
    const float* __restrict__ q, const float* __restrict__ k, const float* __restrict__ v,
    const float* __restrict__ wq, const float* __restrict__ wk,
    const float* __restrict__ wv, const float* __restrict__ wo,
    unsigned short* __restrict__ Xin, unsigned short* __restrict__ Wbf)
{
  const unsigned u = blockIdx.x * 256u + threadIdx.x;   // 3670016 units of 8 elems
  const float* src;
  unsigned short* dst;
  if (u < 3145728u) {                      // q,k,v
    const unsigned z = u >> 20, r = u & 1048575u;
    src = (z == 0 ? q : z == 1 ? k : v) + (size_t)r * 8;
    dst = Xin + (size_t)z * 8388608u + (size_t)r * 8;
  } else {                                 // Wq,Wk,Wv,Wo
    const unsigned u2 = u - 3145728u, wz = u2 >> 17, r = u2 & 131071u;
    src = (wz == 0 ? wq : wz == 1 ? wk : wz == 2 ? wv : wo) + (size_t)r * 8;
    dst = Wbf + (size_t)wz * 1048576u + (size_t)r * 8;
  }
  f32x4 a = *(const f32x4*)src;
  f32x4 b = *(const f32x4*)(src + 4);
  u16x8 o;
  o[0]=bfbits(a[0]); o[1]=bfbits(a[1]); o[2]=bfbits(a[2]); o[3]=bfbits(a[3]);
  o[4]=bfbits(b[0]); o[5]=bfbits(b[1]); o[6]=bfbits(b[2]); o[7]=bfbits(b[3]);
  *(u16x8*)dst = o;
}

// ---------------- mask dtype detection ----------------
__global__ void detect_mask(const unsigned* __restrict__ m, int* __restrict__ flag)
{
  unsigned ok = 1u;
#pragma unroll 8
  for (int i = 0; i < 64; ++i) {
    unsigned w = m[(threadIdx.x << 6) + i];
    ok &= (w <= 1u) ? 1u : 0u;
  }
  unsigned long long vote = __ballot(ok != 0u);
  if (threadIdx.x == 0) *flag = (vote == ~0ull) ? 1 : 0;
}

// ---------------- C[r][e] = sum_c A[r][c]*B[e][c], 2-phase double-buffered ----------------
// 256x128 tile, BK=64, 8 waves (4Mx2N, 64x64 each). LDS 96 KiB (1 block/CU).
// Stage next K-tile first; __syncthreads' vmcnt(0)+lgkmcnt(0) drain is the phase boundary.
template<int OUTF32>
__global__ __launch_bounds__(512) void gemm2ph(
    const unsigned short* __restrict__ A,  // [M][K] bf16
    const unsigned short* __restrict__ B,  // [N][K] bf16
    void* __restrict__ Cv, float scale, int M, int N, int K)
{
  const int tid = threadIdx.x;
  const int w = tid >> 6, lane = tid & 63, c = lane & 15, g = lane >> 4;
  const int wr = w >> 1, wc = w & 1;

  // XCD-chunked swizzle (nwg % 8 == 0 for all our grids)
  const int nwg = gridDim.x, cpx = nwg >> 3, bid = blockIdx.x;
  const int swz = (bid & 7) * cpx + (bid >> 3);
  const int ntx = N >> 7;
  const int bx = swz % ntx, by = swz / ntx;
  const int rowA = by * 256, rowB = bx * 128;

  __shared__ unsigned short As[2][256 * 64];   // 2 x 32 KiB
  __shared__ unsigned short Bs[2][128 * 64];   // 2 x 16 KiB

  f32x4 acc[4][4];
#pragma unroll
  for (int i = 0; i < 4; ++i)
#pragma unroll
    for (int j = 0; j < 4; ++j) acc[i][j] = (f32x4){0.f, 0.f, 0.f, 0.f};

  const int srow = tid >> 3, skc = tid & 7;
  const int wbase = (tid & ~63) * 16;          // wave-uniform LDS byte base

  // prologue: stage K-tile 0 into buf 0
#pragma unroll
  for (int i = 0; i < 4; ++i)
    async16(A + (size_t)(rowA + i * 64 + srow) * K + skc * 8,
            (char*)&As[0][0] + i * 8192 + wbase);
#pragma unroll
  for (int j = 0; j < 2; ++j)
    async16(B + (size_t)(rowB + j * 64 + srow) * K + skc * 8,
            (char*)&Bs[0][0] + j * 8192 + wbase);
  __syncthreads();

  int buf = 0;
  const int nk = K >> 6;
  for (int kt = 0; kt < nk; ++kt) {
    if (kt + 1 < nk) {                        // issue next-tile stage FIRST
      const int k1 = (kt + 1) << 6, bo = buf ^ 1;
#pragma unroll
      for (int i = 0; i < 4; ++i)
        async16(A + (size_t)(rowA + i * 64 + srow) * K + k1 + skc * 8,
                (char*)&As[bo][0] + i * 8192 + wbase);
#pragma unroll
      for (int j = 0; j < 2; ++j)
        async16(B + (size_t)(rowB + j * 64 + srow) * K + k1 + skc * 8,
                (char*)&Bs[bo][0] + j * 8192 + wbase);
    }
    bf16x8 af[4][2], bfr[4][2];
#pragma unroll
    for (int x = 0; x < 4; ++x)
#pragma unroll
      for (int ks = 0; ks < 2; ++ks) {
        af[x][ks]  = *(const bf16x8*)&As[buf][(wr * 64 + x * 16 + c) * 64 + ks * 32 + (g << 3)];
        bfr[x][ks] = *(const bf16x8*)&Bs[buf][(wc * 64 + x * 16 + c) * 64 + ks * 32 + (g << 3)];
      }
#pragma unroll
    for (int ks = 0; ks < 2; ++ks)
#pragma unroll
      for (int mf = 0; mf < 4; ++mf)
#pragma unroll
        for (int nf = 0; nf < 4; ++nf)
          acc[mf][nf] = __builtin_amdgcn_mfma_f32_16x16x32_bf16(af[mf][ks], bfr[nf][ks], acc[mf][nf], 0, 0, 0);
    __syncthreads();                          // drains vmcnt(0): next tile landed
    buf ^= 1;
  }

  const int r0 = rowA + wr * 64, c0 = rowB + wc * 64;
  if (OUTF32) {
    float* O = (float*)Cv;
#pragma unroll
    for (int mf = 0; mf < 4; ++mf)
#pragma unroll
      for (int nf = 0; nf < 4; ++nf)
#pragma unroll
        for (int j = 0; j < 4; ++j)
          O[(size_t)(r0 + mf * 16 + g * 4 + j) * N + c0 + nf * 16 + c] = acc[mf][nf][j] * scale;
  } else {
    unsigned short* O = (unsigned short*)Cv;
#pragma unroll
    for (int mf = 0; mf < 4; ++mf)
#pragma unroll
      for (int nf = 0; nf < 4; ++nf)
#pragma unroll
        for (int j = 0; j < 4; ++j)
          O[(size_t)(r0 + mf * 16 + g * 4 + j) * N + c0 + nf * 16 + c] = bfbits(acc[mf][nf][j] * scale);
  }
}

// ---------------- Vt[bh][d][s] = Vproj[(s*8+b)][h*64+d] ----------------
__global__ __launch_bounds__(256) void transpose_v(
    const unsigned short* __restrict__ Xp2, unsigned short* __restrict__ Vt)
{
  const int tid = threadIdx.x;
  const int bh = blockIdx.y, b = bh >> 4, h = bh & 15;
  const int s0 = blockIdx.x << 6;
  __shared__ unsigned short T[64 * 68];
#pragma unroll
  for (int p = 0; p < 2; ++p) {
    const int idx = (p << 8) + tid, sr = idx >> 3, ch2 = idx & 7;
    *(u16x8*)&T[sr * 68 + ch2 * 8] =
        *(const u16x8*)(Xp2 + ((size_t)((s0 + sr) * 8 + b) << 10) + (h << 6) + ch2 * 8);
  }
  __syncthreads();
#pragma unroll
  for (int p = 0; p < 2; ++p) {
    const int idx = (p << 8) + tid, dr = idx >> 3, ch2 = idx & 7;
    u16x8 o;
#pragma unroll
    for (int e = 0; e < 8; ++e) o[e] = T[(ch2 * 8 + e) * 68 + dr];
    *(u16x8*)(Vt + ((size_t)(bh * 64 + dr) << 10) + s0 + ch2 * 8) = o;
  }
}

// ---------------- mask fragment load (u8 or i32) ----------------
__device__ __forceinline__ void load_mask4(unsigned mv[4], const void* maskp, bool mi32,
                                           size_t base, int g) {
  if (mi32) {
    const int* mrow = (const int*)maskp + base + (g << 2);
#pragma unroll
    for (int mf = 0; mf < 4; ++mf) {
      const int4 w4 = *(const int4*)(mrow + mf * 16);
      mv[mf] = (w4.x ? 1u : 0u) | (w4.y ? 0x100u : 0u) | (w4.z ? 0x10000u : 0u) | (w4.w ? 0x1000000u : 0u);
    }
  } else {
    const unsigned char* mrow = (const unsigned char*)maskp + base + (g << 2);
#pragma unroll
    for (int mf = 0; mf < 4; ++mf) mv[mf] = *(const unsigned*)(mrow + mf * 16);
  }
}

// ---------------- fused flash attention ----------------
// grid (16 qblocks, 128 bh), 256 thr. Wave w owns q-rows [qb0+16w, +16).
// S^T = K*Q^T (softmax rows lane-local, q = lane&15); O^T = V^T * P^T.
__global__ __launch_bounds__(256) void attn_kernel(
    const unsigned short* __restrict__ Qp,   // [8192][1024] bf16, pre-scaled by 1/8
    const unsigned short* __restrict__ Kp,   // [8192][1024] bf16
    const unsigned short* __restrict__ Vt,   // [128][64][1024] bf16
    const void*           __restrict__ maskp,// [128][1024][1024] u8 or i32
    const int*            __restrict__ mflag,
    unsigned short* __restrict__ AO)         // [8192][1024] bf16
{
  const int tid = threadIdx.x;
  const int w = tid >> 6, lane = tid & 63, c = lane & 15, g = lane >> 4;
  const int bh = blockIdx.y, b = bh >> 4, h = bh & 15;
  const int qb0 = blockIdx.x << 6;
  const int qrow = qb0 + (w << 4) + c;
  const bool mi32 = (*mflag != 0);

  __shared__ unsigned short Ksm[64 * 72];       // [kk][d]
  __shared__ unsigned short Vsm[64 * 72];       // [d][kk]
  __shared__ unsigned short Psm[4][16 * 72];    // per-wave P[q][kk]

  bf16x8 qf[2];
  {
    const unsigned short* qp = Qp + ((size_t)(qrow * 8 + b) << 10) + (h << 6) + (g << 3);
    qf[0] = *(const bf16x8*)qp;
    qf[1] = *(const bf16x8*)(qp + 32);
  }

  const int row0 = tid >> 3, ch = tid & 7;
  const unsigned short* Vg = Vt + ((size_t)bh << 16);
  const size_t mbase0 = ((size_t)bh << 20) + ((size_t)qrow << 10);

  bf16x8 kr[2], vr[2];
#pragma unroll
  for (int p = 0; p < 2; ++p) {
    const int r = row0 + p * 32;
    kr[p] = *(const bf16x8*)(Kp + ((size_t)(r * 8 + b) << 10) + (h << 6) + (ch << 3));
    vr[p] = *(const bf16x8*)(Vg + ((size_t)r << 10) + (ch << 3));
  }
  unsigned mv[4];
  load_mask4(mv, maskp, mi32, mbase0, g);       // tile 0 mask prefetch

  f32x4 oacc[4];
#pragma unroll
  for (int i = 0; i < 4; ++i) oacc[i] = (f32x4){0.f, 0.f, 0.f, 0.f};
  float mrun = -1e30f, lrun = 0.f;

  for (int t = 0; t < 16; ++t) {
    const int kk0 = t << 6;
    __syncthreads();
#pragma unroll
    for (int p = 0; p < 2; ++p) {
      const int r = row0 + p * 32;
      *(bf16x8*)&Ksm[r * 72 + (ch << 3)] = kr[p];
      *(bf16x8*)&Vsm[r * 72 + (ch << 3)] = vr[p];
    }
    __syncthreads();
    unsigned mvN[4];
    if (t < 15) {                                // prefetch next tile (K/V/mask)
      const int kk1 = kk0 + 64;
#pragma unroll
      for (int p = 0; p < 2; ++p) {
        const int r = row0 + p * 32;
        kr[p] = *(const bf16x8*)(Kp + ((size_t)((kk1 + r) * 8 + b) << 10) + (h << 6) + (ch << 3));
        vr[p] = *(const bf16x8*)(Vg + ((size_t)r << 10) + kk1 + (ch << 3));
      }
      load_mask4(mvN, maskp, mi32, mbase0 + kk1, g);
    }
    // S^T tile: rows kk = mf*16+g*4+j, col q = c
    f32x4 sacc[4];
#pragma unroll
    for (int i = 0; i < 4; ++i) sacc[i] = (f32x4){0.f, 0.f, 0.f, 0.f};
#pragma unroll
    for (int d2 = 0; d2 < 2; ++d2) {
#pragma unroll
      for (int mf = 0; mf < 4; ++mf) {
        bf16x8 kf = *(const bf16x8*)&Ksm[(mf * 16 + c) * 72 + d2 * 32 + (g << 3)];
        sacc[mf] = __builtin_amdgcn_mfma_f32_16x16x32_bf16(kf, qf[d2], sacc[mf], 0, 0, 0);
      }
    }
    // mask + online softmax
    float tmax = -1e30f;
#pragma unroll
    for (int mf = 0; mf < 4; ++mf)
#pragma unroll
      for (int j = 0; j < 4; ++j) {
        float s = sacc[mf][j];
        if ((mv[mf] >> (8 * j)) & 0xffu) s = -1e30f;
        sacc[mf][j] = s;
        tmax = fmaxf(tmax, s);
      }
    tmax = fmaxf(tmax, __shfl_xor(tmax, 16));
    tmax = fmaxf(tmax, __shfl_xor(tmax, 32));
    const float mnew = fmaxf(mrun, tmax);
    const float alpha = __builtin_amdgcn_exp2f((mrun - mnew) * LOG2E);
    float tsum = 0.f;
    float pv[4][4];
#pragma unroll
    for (int mf = 0; mf < 4; ++mf)
#pragma unroll
      for (int j = 0; j < 4; ++j) {
        const float p = __builtin_amdgcn_exp2f((sacc[mf][j] - mnew) * LOG2E);
        pv[mf][j] = p;
        tsum += p;
      }
    tsum += __shfl_xor(tsum, 16);
    tsum += __shfl_xor(tsum, 32);
    lrun = lrun * alpha + tsum;
    mrun = mnew;
#pragma unroll
    for (int i = 0; i < 4; ++i) {
      oacc[i][0] *= alpha; oacc[i][1] *= alpha; oacc[i][2] *= alpha; oacc[i][3] *= alpha;
    }
#pragma unroll
    for (int mf = 0; mf < 4; ++mf) {
      uint2 t2;
      t2.x = pk2(pv[mf][0], pv[mf][1]);
      t2.y = pk2(pv[mf][2], pv[mf][3]);
      *(uint2*)&Psm[w][c * 72 + mf * 16 + (g << 2)] = t2;
    }
#pragma unroll
    for (int ks = 0; ks < 2; ++ks) {
      bf16x8 pf = *(const bf16x8*)&Psm[w][c * 72 + ks * 32 + (g << 3)];
#pragma unroll
      for (int mf = 0; mf < 4; ++mf) {
        bf16x8 vf = *(const bf16x8*)&Vsm[(mf * 16 + c) * 72 + ks * 32 + (g << 3)];
        oacc[mf] = __builtin_amdgcn_mfma_f32_16x16x32_bf16(vf, pf, oacc[mf], 0, 0, 0);
      }
    }
    if (t < 15) {
      mv[0] = mvN[0]; mv[1] = mvN[1]; mv[2] = mvN[2]; mv[3] = mvN[3];
    }
  }
  const float inv = 1.0f / lrun;
#pragma unroll
  for (int mf = 0; mf < 4; ++mf) {
    uint2 t2;
    t2.x = pk2(oacc[mf][0] * inv, oacc[mf][1] * inv);
    t2.y = pk2(oacc[mf][2] * inv, oacc[mf][3] * inv);
    *(uint2*)(AO + ((size_t)(qrow * 8 + b) << 10) + (h << 6) + mf * 16 + (g << 2)) = t2;
  }
}

// ---------------- host ----------------
extern "C" void kernel_launch(void* const* d_in, const int* in_sizes, int n_in,
                              void* d_out, int out_size, void* d_ws, size_t ws_size,
                              hipStream_t stream)
{
  const float* q  = (const float*)d_in[0];
  const float* k  = (const float*)d_in[1];
  const float* v  = (const float*)d_in[2];
  const void*  mask = (const void*)d_in[3];
  const float* wq = (const float*)d_in[4];
  const float* wk = (const float*)d_in[5];
  const float* wv = (const float*)d_in[6];
  const float* wo = (const float*)d_in[7];

  unsigned short* ws  = (unsigned short*)d_ws;   // needs 104 MiB
  unsigned short* Xin = ws;                      // 3 x 8388608 (bf16 q,k,v)
  unsigned short* Wbf = ws + 25165824u;          // 4 x 1048576
  unsigned short* Xp  = ws + 29360128u;          // 3 x 8388608 (projected)
  unsigned short* Vt  = ws + 8388608u;           // aliases Xin[1] (dead after K projection)
  unsigned short* AO  = ws;                      // aliases Xin[0] (dead after Q projection)
  int* mfl            = (int*)(ws + 16777216u);  // aliases Xin[2] (dead after V projection)

  cvt_kernel<<<14336, 256, 0, stream>>>(q, k, v, wq, wk, wv, wo, Xin, Wbf);
  gemm2ph<0><<<256, 512, 0, stream>>>(Xin,             Wbf,            Xp,             0.125f, 8192, 1024, 1024);
  gemm2ph<0><<<256, 512, 0, stream>>>(Xin + 8388608u,  Wbf + 1048576u, Xp + 8388608u,  1.0f,   8192, 1024, 1024);
  gemm2ph<0><<<256, 512, 0, stream>>>(Xin + 16777216u, Wbf + 2097152u, Xp + 16777216u, 1.0f,   8192, 1024, 1024);
  detect_mask<<<1, 64, 0, stream>>>((const unsigned*)mask, mfl);
  transpose_v<<<dim3(16, 128), 256, 0, stream>>>(Xp + 16777216u, Vt);
  attn_kernel<<<dim3(16, 128), 256, 0, stream>>>(Xp, Xp + 8388608u, Vt, mask, mfl, AO);
  gemm2ph<1><<<256, 512, 0, stream>>>(AO, Wbf + 3145728u, d_out, 1.0f, 8192, 1024, 1024);
}